// Round 4
// baseline (59.727 us; speedup 1.0000x reference)
//
#include <hip/hip_runtime.h>

#define IOU_THR 0.7f
#define FILT_C  0.69985f   // conservative filter coeff: 0.7*(1-2e-4)

__device__ __forceinline__ unsigned long long make_key(unsigned int sbits,
                                                       unsigned int idx) {
    // descending score, ascending index tie-break (stable argsort(-score))
    return (((unsigned long long)(~sbits)) << 32) | idx;
}

// ---------------------------------------------------------------------------
// Kernel A: partial rank counts, 4 i-keys per thread, NO atomics.
// grid = (N/1024, N/256), block = 256.
// partial[y][i] = #{keys in y-tile} < key_i   (each cell written once)
// ---------------------------------------------------------------------------
__global__ void nms_rank_partial(const float* __restrict__ score,
                                 unsigned int* __restrict__ partial, int N)
{
    __shared__ unsigned long long skeys[256];
    const int tid = threadIdx.x;
    const int y   = blockIdx.y;
    const int t   = y * 256 + tid;
    skeys[tid] = make_key(__float_as_uint(score[t]), (unsigned int)t);

    const int i0 = blockIdx.x * 1024 + tid;
    const unsigned long long k0 = make_key(__float_as_uint(score[i0      ]), i0      );
    const unsigned long long k1 = make_key(__float_as_uint(score[i0 + 256]), i0 + 256);
    const unsigned long long k2 = make_key(__float_as_uint(score[i0 + 512]), i0 + 512);
    const unsigned long long k3 = make_key(__float_as_uint(score[i0 + 768]), i0 + 768);
    __syncthreads();

    unsigned int c0 = 0, c1 = 0, c2 = 0, c3 = 0;
    #pragma unroll 8
    for (int k = 0; k < 256; ++k) {
        const unsigned long long ok = skeys[k];
        c0 += (ok < k0) ? 1u : 0u;
        c1 += (ok < k1) ? 1u : 0u;
        c2 += (ok < k2) ? 1u : 0u;
        c3 += (ok < k3) ? 1u : 0u;
    }
    unsigned int* row = partial + (size_t)y * N;
    row[i0      ] = c0;
    row[i0 + 256] = c1;
    row[i0 + 512] = c2;
    row[i0 + 768] = c3;
}

// ---------------------------------------------------------------------------
// Kernel B: reduce partial ranks, scatter box + area to sorted slot,
// and zero the suppression mask (runs before suppress in-stream).
// ---------------------------------------------------------------------------
__global__ void nms_scatter(const float4* __restrict__ bbox,
                            const unsigned int* __restrict__ partial,
                            float4* __restrict__ sortedBox,
                            float* __restrict__ sortedArea,
                            unsigned int* __restrict__ mask, int N)
{
    const int i = blockIdx.x * 256 + threadIdx.x;
    unsigned int r = 0;
    const int ny = N / 256;
    for (int y = 0; y < ny; ++y)
        r += partial[(size_t)y * N + i];
    const float4 b = bbox[i];
    sortedBox[r]  = b;
    sortedArea[r] = (b.z - b.x) * (b.w - b.y);   // (y2-y1)*(x2-x1)
    mask[i] = 0u;
}

// ---------------------------------------------------------------------------
// Kernel C: suppressed[j] |= any i<j with IoU > 0.7.
// 1D triangular grid over (bi <= bj) tile pairs.
// Off-diagonal: 4 waves split the i-tile (64 each), each lane owns 4 j's ->
// one LDS broadcast feeds 4 pair-evals (VALU-bound, not LDS-bound).
// Diagonal: 1 j per thread, k < tid (rare: 32 of 528 blocks).
// Cheap conservative filter gates the exact IEEE-division path.
// ---------------------------------------------------------------------------
__global__ void nms_suppress(const float4* __restrict__ sortedBox,
                             const float* __restrict__ sortedArea,
                             unsigned int* __restrict__ mask)
{
    // decode triangular index: x = bj*(bj+1)/2 + bi, bi <= bj
    const int x = blockIdx.x;
    int bj = (int)((sqrtf(8.0f * (float)x + 1.0f) - 1.0f) * 0.5f);
    while ((bj + 1) * (bj + 2) / 2 <= x) ++bj;
    while (bj * (bj + 1) / 2 > x) --bj;
    const int bi = x - bj * (bj + 1) / 2;

    __shared__ float4 tile[256];
    __shared__ float  tpai[256];          // FILT_C * area_i
    const int tid = threadIdx.x;

    tile[tid] = sortedBox[bi * 256 + tid];
    tpai[tid] = FILT_C * sortedArea[bi * 256 + tid];
    __syncthreads();

    if (bi == bj) {
        const int j = bj * 256 + tid;
        const float4 bb = sortedBox[j];
        const float  paj = FILT_C * sortedArea[j];
        unsigned int sup = 0u;
        for (int k = 0; k < tid; ++k) {
            const float4 bo = tile[k];
            const float iy1 = fmaxf(bo.x, bb.x);
            const float ix1 = fmaxf(bo.y, bb.y);
            const float iy2 = fminf(bo.z, bb.z);
            const float ix2 = fminf(bo.w, bb.w);
            const float ih  = fmaxf(iy2 - iy1, 0.0f);
            const float iw  = fmaxf(ix2 - ix1, 0.0f);
            float inter = ih * iw;
            if (fmaf(inter, 1.7f, -(tpai[k] + paj)) > 0.0f) {
                // exact path: per-op rounding identical to numpy
                float ai = (bo.z - bo.x) * (bo.w - bo.y);
                float aj = (bb.z - bb.x) * (bb.w - bb.y);
                asm volatile("" : "+v"(ai));
                asm volatile("" : "+v"(aj));
                asm volatile("" : "+v"(inter));
                float s = ai + aj;
                asm volatile("" : "+v"(s));
                const float uni = s - inter;
                sup |= (inter / uni > IOU_THR) ? 1u : 0u;
            }
        }
        if (sup) atomicOr(&mask[j], 1u);
    } else {
        const int w = tid >> 6;           // wave id: i-quarter
        const int l = tid & 63;
        float4 jb[4];
        float  paj[4];
        #pragma unroll
        for (int m = 0; m < 4; ++m) {
            const int j = bj * 256 + m * 64 + l;
            jb[m]  = sortedBox[j];
            paj[m] = FILT_C * sortedArea[j];
        }
        unsigned int sup[4] = {0u, 0u, 0u, 0u};
        const int kbase = w * 64;
        for (int k = 0; k < 64; ++k) {
            const float4 bo  = tile[kbase + k];
            const float  pai = tpai[kbase + k];
            #pragma unroll
            for (int m = 0; m < 4; ++m) {
                const float iy1 = fmaxf(bo.x, jb[m].x);
                const float ix1 = fmaxf(bo.y, jb[m].y);
                const float iy2 = fminf(bo.z, jb[m].z);
                const float ix2 = fminf(bo.w, jb[m].w);
                const float ih  = fmaxf(iy2 - iy1, 0.0f);
                const float iw  = fmaxf(ix2 - ix1, 0.0f);
                float inter = ih * iw;
                if (fmaf(inter, 1.7f, -(pai + paj[m])) > 0.0f) {
                    float ai = (bo.z - bo.x) * (bo.w - bo.y);
                    float aj = (jb[m].z - jb[m].x) * (jb[m].w - jb[m].y);
                    asm volatile("" : "+v"(ai));
                    asm volatile("" : "+v"(aj));
                    asm volatile("" : "+v"(inter));
                    float s = ai + aj;
                    asm volatile("" : "+v"(s));
                    const float uni = s - inter;
                    sup[m] |= (inter / uni > IOU_THR) ? 1u : 0u;
                }
            }
        }
        #pragma unroll
        for (int m = 0; m < 4; ++m)
            if (sup[m]) atomicOr(&mask[bj * 256 + m * 64 + l], 1u);
    }
}

// ---------------------------------------------------------------------------
// Kernel D: keep = !suppressed; write masked sorted boxes + keep flags.
// d_out layout: [N*4 floats boxes][N floats keep].
// ---------------------------------------------------------------------------
__global__ void nms_output(const float4* __restrict__ sortedBox,
                           const unsigned int* __restrict__ mask,
                           float* __restrict__ out, int N)
{
    const int j = blockIdx.x * 256 + threadIdx.x;
    const float s = (mask[j] == 0u) ? 1.0f : 0.0f;
    const float4 b = sortedBox[j];
    float4 o;
    o.x = b.x * s; o.y = b.y * s; o.z = b.z * s; o.w = b.w * s;
    ((float4*)out)[j] = o;
    out[N * 4 + j] = s;
}

extern "C" void kernel_launch(void* const* d_in, const int* in_sizes, int n_in,
                              void* d_out, int out_size, void* d_ws, size_t ws_size,
                              hipStream_t stream) {
    const float* bbox  = (const float*)d_in[0];   // [1, N, 4] (y1,x1,y2,x2)
    const float* score = (const float*)d_in[1];   // [1, N]
    const int N = in_sizes[1];                    // 8192
    const int nb = N / 256;                       // 32

    char* ws = (char*)d_ws;
    float4*       sortedBox  = (float4*)ws;                               // N*16 B
    float*        sortedArea = (float*)(ws + (size_t)N * 16);             // N*4 B
    unsigned int* mask       = (unsigned int*)(ws + (size_t)N * 20);      // N*4 B
    unsigned int* partial    = (unsigned int*)(ws + (size_t)N * 24);      // nb*N*4 B

    nms_rank_partial<<<dim3(N / 1024, nb), 256, 0, stream>>>(score, partial, N);
    nms_scatter<<<nb, 256, 0, stream>>>((const float4*)bbox, partial,
                                        sortedBox, sortedArea, mask, N);
    nms_suppress<<<nb * (nb + 1) / 2, 256, 0, stream>>>(sortedBox, sortedArea,
                                                        mask);
    nms_output<<<nb, 256, 0, stream>>>(sortedBox, mask, (float*)d_out, N);
}

// Round 5
// 40.611 us; speedup vs baseline: 1.4707x; 1.4707x over previous
//
#include <hip/hip_runtime.h>

// Exact decision boundary for  RN_f32(inter/uni) > (float)0.7 :
//   c = 0.7f = 0x3f333333, succ(c) = 0x3f333334 (even mantissa).
//   RN(x) > c  <=>  x >= M  where M = (c + succ(c))/2  (tie rounds to even
//   = succ(c) > c, so ">=" is correct).  M = 23488103 * 2^-25 (25 sig bits),
//   uni has <=24 sig bits  =>  M*(double)uni is EXACT, comparison is exact.
//   uni >= 2 always here (every box area >= 1), so uni==0 never occurs.
#define M_BOUND 0.7000000178813934326171875

__device__ __forceinline__ unsigned long long make_key(unsigned int sbits,
                                                       unsigned int idx) {
    // descending score, ascending index tie-break (stable argsort(-score))
    return (((unsigned long long)(~sbits)) << 32) | idx;
}

// ---------------------------------------------------------------------------
// Kernel A: partial rank counts, 2 i-keys per thread, no atomics.
// grid = (N/512, N/256) = 512 blocks -> 2 blocks/CU, 2 waves/SIMD.
// partial[y][i] = #{keys in y-tile < key_i}   (each cell written once)
// ---------------------------------------------------------------------------
__global__ void nms_rank_partial(const float* __restrict__ score,
                                 unsigned int* __restrict__ partial, int N)
{
    __shared__ unsigned long long skeys[256];
    const int tid = threadIdx.x;
    const int y   = blockIdx.y;
    const int t   = y * 256 + tid;
    skeys[tid] = make_key(__float_as_uint(score[t]), (unsigned int)t);

    const int i0 = blockIdx.x * 512 + tid;
    const unsigned long long k0 = make_key(__float_as_uint(score[i0      ]), i0      );
    const unsigned long long k1 = make_key(__float_as_uint(score[i0 + 256]), i0 + 256);
    __syncthreads();

    unsigned int c0 = 0, c1 = 0;
    #pragma unroll 16
    for (int k = 0; k < 256; ++k) {
        const unsigned long long ok = skeys[k];
        c0 += (ok < k0) ? 1u : 0u;
        c1 += (ok < k1) ? 1u : 0u;
    }
    unsigned int* row = partial + (size_t)y * N;
    row[i0      ] = c0;
    row[i0 + 256] = c1;
}

// ---------------------------------------------------------------------------
// Kernel B: reduce partial ranks (32 independent loads -> MLP covers
// latency), scatter box + area to sorted slot, zero the suppression mask.
// ---------------------------------------------------------------------------
__global__ void nms_scatter(const float4* __restrict__ bbox,
                            const unsigned int* __restrict__ partial,
                            float4* __restrict__ sortedBox,
                            float* __restrict__ sortedArea,
                            unsigned int* __restrict__ mask, int N)
{
    const int i = blockIdx.x * 256 + threadIdx.x;
    const int ny = N / 256;
    unsigned int r = 0;
    #pragma unroll 8
    for (int y = 0; y < ny; ++y)
        r += partial[(size_t)y * N + i];
    const float4 b = bbox[i];
    sortedBox[r]  = b;
    sortedArea[r] = (b.z - b.x) * (b.w - b.y);   // (y2-y1)*(x2-x1), once (as np)
    mask[i] = 0u;
}

// ---------------------------------------------------------------------------
// Kernel C: suppressed[j] |= any i<j with IoU > 0.7.  FULLY BRANCHLESS body:
// no divide (exact f64 boundary compare), no filter branch, so the 64-iter
// k-loop unrolls and software-pipelines.  1D triangular grid (bi <= bj);
// 4 waves split the i-tile (64 k's each), each lane owns 4 j's -> one LDS
// broadcast feeds 4 pair-evals.  Diagonal tiles use the same path with a
// branchless (i<j) predicate.
// ---------------------------------------------------------------------------
__global__ __launch_bounds__(256)
void nms_suppress(const float4* __restrict__ sortedBox,
                  const float* __restrict__ sortedArea,
                  unsigned int* __restrict__ mask)
{
    // decode triangular index: x = bj*(bj+1)/2 + bi, bi <= bj
    const int x = blockIdx.x;
    int bj = (int)((sqrtf(8.0f * (float)x + 1.0f) - 1.0f) * 0.5f);
    while ((bj + 1) * (bj + 2) / 2 <= x) ++bj;
    while (bj * (bj + 1) / 2 > x) --bj;
    const int bi = x - bj * (bj + 1) / 2;

    __shared__ float4 tile[256];
    __shared__ float  tarea[256];
    const int tid = threadIdx.x;

    tile[tid]  = sortedBox[bi * 256 + tid];
    tarea[tid] = sortedArea[bi * 256 + tid];
    __syncthreads();

    const int w = tid >> 6;           // wave id: k-quarter of the i-tile
    const int l = tid & 63;
    const bool offdiag = (bi < bj);

    float4 jb[4];
    float  aj[4];
    #pragma unroll
    for (int m = 0; m < 4; ++m) {
        const int j = bj * 256 + m * 64 + l;
        jb[m] = sortedBox[j];
        aj[m] = sortedArea[j];
    }

    unsigned int sup[4] = {0u, 0u, 0u, 0u};
    const int kbase = w * 64;
    #pragma unroll 2
    for (int k = 0; k < 64; ++k) {
        const float4 bo = tile[kbase + k];
        const float  ai = tarea[kbase + k];
        const int    ig = kbase + k;          // local i index within tile
        #pragma unroll
        for (int m = 0; m < 4; ++m) {
            const float iy1 = fmaxf(bo.x, jb[m].x);
            const float ix1 = fmaxf(bo.y, jb[m].y);
            const float iy2 = fminf(bo.z, jb[m].z);
            const float ix2 = fminf(bo.w, jb[m].w);
            const float ih  = fmaxf(iy2 - iy1, 0.0f);
            const float iw  = fmaxf(ix2 - ix1, 0.0f);
            float inter = ih * iw;
            asm volatile("" : "+v"(inter));   // block s - ih*iw -> fma
            const float s   = ai + aj[m];     // operands from memory: no fma
            const float uni = s - inter;
            const bool hit  = ((double)inter >= M_BOUND * (double)uni);
            const bool pred = offdiag || (ig < m * 64 + l);   // i<j on diag
            sup[m] |= (hit && pred) ? 1u : 0u;
        }
    }
    #pragma unroll
    for (int m = 0; m < 4; ++m)
        if (sup[m]) atomicOr(&mask[bj * 256 + m * 64 + l], 1u);
}

// ---------------------------------------------------------------------------
// Kernel D: keep = !suppressed; write masked sorted boxes + keep flags.
// d_out layout: [N*4 floats boxes][N floats keep].
// ---------------------------------------------------------------------------
__global__ void nms_output(const float4* __restrict__ sortedBox,
                           const unsigned int* __restrict__ mask,
                           float* __restrict__ out, int N)
{
    const int j = blockIdx.x * 256 + threadIdx.x;
    const float s = (mask[j] == 0u) ? 1.0f : 0.0f;
    const float4 b = sortedBox[j];
    float4 o;
    o.x = b.x * s; o.y = b.y * s; o.z = b.z * s; o.w = b.w * s;
    ((float4*)out)[j] = o;
    out[N * 4 + j] = s;
}

extern "C" void kernel_launch(void* const* d_in, const int* in_sizes, int n_in,
                              void* d_out, int out_size, void* d_ws, size_t ws_size,
                              hipStream_t stream) {
    const float* bbox  = (const float*)d_in[0];   // [1, N, 4] (y1,x1,y2,x2)
    const float* score = (const float*)d_in[1];   // [1, N]
    const int N = in_sizes[1];                    // 8192
    const int nb = N / 256;                       // 32

    char* ws = (char*)d_ws;
    float4*       sortedBox  = (float4*)ws;                               // N*16 B
    float*        sortedArea = (float*)(ws + (size_t)N * 16);             // N*4 B
    unsigned int* mask       = (unsigned int*)(ws + (size_t)N * 20);      // N*4 B
    unsigned int* partial    = (unsigned int*)(ws + (size_t)N * 24);      // nb*N*4 B

    nms_rank_partial<<<dim3(N / 512, nb), 256, 0, stream>>>(score, partial, N);
    nms_scatter<<<nb, 256, 0, stream>>>((const float4*)bbox, partial,
                                        sortedBox, sortedArea, mask, N);
    nms_suppress<<<nb * (nb + 1) / 2, 256, 0, stream>>>(sortedBox, sortedArea,
                                                        mask);
    nms_output<<<nb, 256, 0, stream>>>(sortedBox, mask, (float*)d_out, N);
}